// Round 3
// baseline (496.888 us; speedup 1.0000x reference)
//
#include <hip/hip_runtime.h>
#include <hip/hip_bf16.h>

// Problem constants (from reference)
#define BATCH 16384
#define DIM   128
#define HID   1024
#define NK    8
#define OPD   25          // 3*K+1
#define N3    (DIM*OPD)   // 3200

typedef __attribute__((ext_vector_type(8))) short  short8;   // 8 bf16 (4 VGPRs)
typedef __attribute__((ext_vector_type(4))) float  floatx4;  // MFMA C/D frag
typedef unsigned int u32;

// async global->LDS, 16B per lane. HW semantics: dst = wave-uniform base +
// lane*16 (m104/m108) — LDS layout below is dense row-major in lane order.
__device__ __forceinline__ void async_copy16(const unsigned short* g,
                                             unsigned short* l) {
    __builtin_amdgcn_global_load_lds(
        (const __attribute__((address_space(1))) u32*)g,
        (__attribute__((address_space(3))) u32*)l,
        16, 0, 0);
}

// ---------------------------------------------------------------- prep kernels
__global__ void cvt_bf16_kernel(const float* __restrict__ in,
                                __hip_bfloat16* __restrict__ out, int n) {
    int i = blockIdx.x * blockDim.x + threadIdx.x;
    if (i < n) out[i] = __float2bfloat16(in[i]);
}

__global__ void maskmul_bf16_kernel(const float* __restrict__ w,
                                    const float* __restrict__ m,
                                    __hip_bfloat16* __restrict__ out, int n) {
    int i = blockIdx.x * blockDim.x + threadIdx.x;
    if (i < n) out[i] = __float2bfloat16(w[i] * m[i]);
}

// ---------------------------------------------------------------- GEMM
// C[M,N] = A[M,K] * Bw[N,K]^T  (+bias, optional silu->bf16)
// 128x128 tile, BK=64, 256 threads (4 waves, 2x2), each wave 64x64 via 4x4
// mfma_f32_16x16x32_bf16 frags. Staging via global_load_lds width=16 (m97).
// A frag: lane reads A[m = lane&15][k = (lane>>4)*8 + j]
// B frag: lane reads Bw[n = lane&15][k = (lane>>4)*8 + j]
// C/D:    col = lane&15, row = (lane>>4)*4 + reg      [verified m89/m91]
template<int SILU>
__global__ __launch_bounds__(256) void gemm_bt_kernel(
    const unsigned short* __restrict__ A,   // M x K bf16 bits
    const unsigned short* __restrict__ Bw,  // N x K bf16 bits
    const float* __restrict__ bias,         // N
    void* __restrict__ Cout,                // SILU? bf16 : float, M x N
    int M, int N, int Kd)
{
    constexpr int BM = 128, BN = 128, BK = 64;
    // dense row-major (no pad) — required by global_load_lds lane mapping
    __shared__ unsigned short As[BM * BK];   // 16 KB
    __shared__ unsigned short Bs[BN * BK];   // 16 KB

    const int bn = blockIdx.x * BN;
    const int bm = blockIdx.y * BM;
    const int t    = threadIdx.x;
    const int lane = t & 63;
    const int w    = t >> 6;
    const int wr   = (w >> 1) * 64;   // wave m offset in tile
    const int wc   = (w & 1) * 64;    // wave n offset in tile
    const int lr   = lane & 15;
    const int quad = lane >> 4;

    floatx4 acc[4][4] = {};

    // staging: 16 chunks of 1024B per tile; wave w owns chunks w*4..w*4+3.
    // chunk q covers rows q*8..q*8+7; lane l -> row q*8 + l/8, col (l%8)*8.
    const int lrow = lane >> 3;        // 0..7
    const int lcol = (lane & 7) * 8;   // shorts, 0..56

    for (int k0 = 0; k0 < Kd; k0 += BK) {
        __syncthreads();               // previous compute done before overwrite
        #pragma unroll
        for (int p = 0; p < 4; p++) {
            const int q = w * 4 + p;
            const int r = q * 8 + lrow;
            async_copy16(&A[(size_t)(bm + r) * Kd + k0 + lcol],
                         &As[q * 512 + lane * 8]);
            async_copy16(&Bw[(size_t)(bn + r) * Kd + k0 + lcol],
                         &Bs[q * 512 + lane * 8]);
        }
        __syncthreads();               // drains vmcnt -> tiles visible
        #pragma unroll
        for (int ks = 0; ks < BK; ks += 32) {
            short8 af[4], bfr[4];
            #pragma unroll
            for (int i = 0; i < 4; i++)
                af[i] = *(const short8*)&As[(wr + i * 16 + lr) * BK + ks + quad * 8];
            #pragma unroll
            for (int j = 0; j < 4; j++)
                bfr[j] = *(const short8*)&Bs[(wc + j * 16 + lr) * BK + ks + quad * 8];
            #pragma unroll
            for (int i = 0; i < 4; i++)
                #pragma unroll
                for (int j = 0; j < 4; j++)
                    acc[i][j] = __builtin_amdgcn_mfma_f32_16x16x32_bf16(
                        af[i], bfr[j], acc[i][j], 0, 0, 0);
        }
    }

    // epilogue
    #pragma unroll
    for (int j = 0; j < 4; j++) {
        const int col = bn + wc + j * 16 + lr;
        const float bv = bias[col];
        #pragma unroll
        for (int i = 0; i < 4; i++) {
            const int rowb = bm + wr + i * 16 + quad * 4;
            #pragma unroll
            for (int r = 0; r < 4; r++) {
                float v = acc[i][j][r] + bv;
                const size_t idx = (size_t)(rowb + r) * N + col;
                if (SILU) {
                    v = v / (1.f + expf(-v));
                    ((__hip_bfloat16*)Cout)[idx] = __float2bfloat16(v);
                } else {
                    ((float*)Cout)[idx] = v;
                }
            }
        }
    }
}

// ---------------------------------------------------------------- spline
// One block per batch row, one thread per dim. Row staged via coalesced
// float4 loads into LDS; per-thread reads at stride 25 dwords (25 coprime 32
// -> 2-way bank aliasing = free). All K=8 arrays fully unrolled.
__global__ __launch_bounds__(128) void spline_kernel(
    const float* __restrict__ raw, const float* __restrict__ x,
    float* __restrict__ out, float* __restrict__ lad)
{
    __shared__ float rowbuf[N3];   // 12.8 KB
    const int b = blockIdx.x;
    const int d = threadIdx.x;

    const float4* src = (const float4*)(raw + (size_t)b * N3);
    for (int i = threadIdx.x; i < N3 / 4; i += 128)
        ((float4*)rowbuf)[i] = src[i];
    __syncthreads();

    const float* r = rowbuf + d * OPD;

    float uw[NK], uh[NK], ud[NK + 1];
    #pragma unroll
    for (int j = 0; j < NK; j++)     uw[j] = r[j];
    #pragma unroll
    for (int j = 0; j < NK; j++)     uh[j] = r[NK + j];
    #pragma unroll
    for (int j = 0; j < NK + 1; j++) ud[j] = r[2 * NK + j];

    float cw[NK + 1], ch[NK + 1], dd[NK + 1];
    // widths: softmax -> affine -> cumsum -> normalize
    {
        float mx = uw[0];
        #pragma unroll
        for (int j = 1; j < NK; j++) mx = fmaxf(mx, uw[j]);
        float e[NK], s = 0.f;
        #pragma unroll
        for (int j = 0; j < NK; j++) { e[j] = expf(uw[j] - mx); s += e[j]; }
        const float inv = 1.f / s;
        cw[0] = 0.f;
        #pragma unroll
        for (int j = 0; j < NK; j++) cw[j + 1] = cw[j] + (0.001f + 0.992f * e[j] * inv);
        const float icn = 1.f / fmaxf(cw[NK], 1e-12f);
        #pragma unroll
        for (int j = 0; j <= NK; j++) cw[j] *= icn;
    }
    // heights: same
    {
        float mx = uh[0];
        #pragma unroll
        for (int j = 1; j < NK; j++) mx = fmaxf(mx, uh[j]);
        float e[NK], s = 0.f;
        #pragma unroll
        for (int j = 0; j < NK; j++) { e[j] = expf(uh[j] - mx); s += e[j]; }
        const float inv = 1.f / s;
        ch[0] = 0.f;
        #pragma unroll
        for (int j = 0; j < NK; j++) ch[j + 1] = ch[j] + (0.001f + 0.992f * e[j] * inv);
        const float icn = 1.f / fmaxf(ch[NK], 1e-12f);
        #pragma unroll
        for (int j = 0; j <= NK; j++) ch[j] *= icn;
    }
    // derivatives: 0.001 + softplus
    #pragma unroll
    for (int j = 0; j <= NK; j++) {
        const float u = ud[j];
        dd[j] = 0.001f + ((u > 20.f) ? u : log1pf(expf(u)));
    }

    const float xv = x[(size_t)b * DIM + d];
    const bool inside = (xv >= -3.f) && (xv <= 3.f);
    float xs = (xv + 3.f) * (1.f / 6.f);
    xs = fminf(fmaxf(xs, 0.f), 1.f);

    int bid = 0;   // cw[0]=0 <= xs always
    #pragma unroll
    for (int j = 1; j <= NK; j++) if (xs >= cw[j]) bid = j;
    if (bid > NK - 1) bid = NK - 1;

    float xk = 0.f, wk = 0.f, yk = 0.f, hk = 0.f, dk = 0.f, dk1 = 0.f;
    #pragma unroll
    for (int j = 0; j < NK; j++) if (bid == j) {
        xk = cw[j]; wk = cw[j + 1] - cw[j];
        yk = ch[j]; hk = ch[j + 1] - ch[j];
        dk = dd[j]; dk1 = dd[j + 1];
    }

    float t = (xs - xk) / (wk + 1e-12f);
    t = fminf(fmaxf(t, 0.f), 1.f);
    const float a   = (hk + 1e-12f) / (wk + 1e-12f);
    const float omt = 1.f - t;
    const float tt1 = t * omt;
    const float num = a * t * t + dk * tt1;
    const float den = a + (dk + dk1 - 2.f * a) * tt1;
    const float s   = num / (den + 1e-12f);
    const float y   = (yk + hk * s) * 6.f - 3.f;
    const float dnum = a * a * (dk1 * t * t + 2.f * a * tt1 + dk * omt * omt);
    const float dydx = dnum / (den * den + 1e-12f);

    out[(size_t)b * DIM + d] = inside ? y : xv;
    float l = inside ? logf(fmaxf(dydx, 1e-12f)) : 0.f;

    // logdet reduction over 128 threads (2 waves)
    #pragma unroll
    for (int off = 32; off > 0; off >>= 1) l += __shfl_down(l, off, 64);
    __shared__ float lsum[2];
    if ((threadIdx.x & 63) == 0) lsum[threadIdx.x >> 6] = l;
    __syncthreads();
    if (threadIdx.x == 0) lad[b] = lsum[0] + lsum[1];
}

// ---------------------------------------------------------------- launch
extern "C" void kernel_launch(void* const* d_in, const int* in_sizes, int n_in,
                              void* d_out, int out_size, void* d_ws, size_t ws_size,
                              hipStream_t stream) {
    const float* x  = (const float*)d_in[0];
    const float* W1 = (const float*)d_in[1];
    const float* b1 = (const float*)d_in[2];
    const float* W2 = (const float*)d_in[3];
    const float* b2 = (const float*)d_in[4];
    const float* W3 = (const float*)d_in[5];
    const float* b3 = (const float*)d_in[6];
    const float* m1 = (const float*)d_in[7];
    const float* m2 = (const float*)d_in[8];
    const float* m3 = (const float*)d_in[9];

    // ---- adaptive batch chunking so the workspace always fits ----
    // static (weights, bf16): w1b 256KB + w2b 2MB + w3b 6.25MB = 8,912,896 B
    // per-chunk C: xb 256C + h1b 2048C + h2b 2048C + raw(fp32) 12800C = 17152C
    constexpr size_t W_BYTES = (size_t)HID * DIM * 2 + (size_t)HID * HID * 2
                             + (size_t)N3 * HID * 2;             // 8,912,896
    int C = BATCH;
    while (C > 512 && W_BYTES + (size_t)17152 * C > ws_size) C >>= 1;
    // C=16384 -> 290MB, 8192 -> 149MB, 4096 -> 79MB, 2048 -> 44MB, 1024 -> 26.5MB

    char* ws = (char*)d_ws;
    const size_t OFF_W1B = 0;
    const size_t OFF_W2B = OFF_W1B + (size_t)HID * DIM * 2;
    const size_t OFF_W3B = OFF_W2B + (size_t)HID * HID * 2;
    const size_t OFF_XB  = OFF_W3B + (size_t)N3 * HID * 2;       // 8,912,896
    const size_t OFF_H1B = OFF_XB  + (size_t)C * DIM * 2;
    const size_t OFF_H2B = OFF_H1B + (size_t)C * HID * 2;
    const size_t OFF_RAW = OFF_H2B + (size_t)C * HID * 2;

    __hip_bfloat16* w1b = (__hip_bfloat16*)(ws + OFF_W1B);
    __hip_bfloat16* w2b = (__hip_bfloat16*)(ws + OFF_W2B);
    __hip_bfloat16* w3b = (__hip_bfloat16*)(ws + OFF_W3B);
    __hip_bfloat16* xb  = (__hip_bfloat16*)(ws + OFF_XB);
    __hip_bfloat16* h1b = (__hip_bfloat16*)(ws + OFF_H1B);
    __hip_bfloat16* h2b = (__hip_bfloat16*)(ws + OFF_H2B);
    float*          raw = (float*)(ws + OFF_RAW);

    // weight prep (once)
    maskmul_bf16_kernel<<<(HID * DIM) / 256, 256, 0, stream>>>(W1, m1, w1b, HID * DIM);
    maskmul_bf16_kernel<<<(HID * HID) / 256, 256, 0, stream>>>(W2, m2, w2b, HID * HID);
    maskmul_bf16_kernel<<<(N3 * HID) / 256, 256, 0, stream>>>(W3, m3, w3b, N3 * HID);

    float* out_p = (float*)d_out;
    float* lad_p = out_p + (size_t)BATCH * DIM;

    for (int cs = 0; cs < BATCH; cs += C) {
        const float* xc = x + (size_t)cs * DIM;
        cvt_bf16_kernel<<<(C * DIM) / 256, 256, 0, stream>>>(xc, xb, C * DIM);
        gemm_bt_kernel<1><<<dim3(HID / 128, C / 128), 256, 0, stream>>>(
            (const unsigned short*)xb, (const unsigned short*)w1b, b1, h1b,
            C, HID, DIM);
        gemm_bt_kernel<1><<<dim3(HID / 128, C / 128), 256, 0, stream>>>(
            (const unsigned short*)h1b, (const unsigned short*)w2b, b2, h2b,
            C, HID, HID);
        gemm_bt_kernel<0><<<dim3(N3 / 128, C / 128), 256, 0, stream>>>(
            (const unsigned short*)h2b, (const unsigned short*)w3b, b3, raw,
            C, N3, HID);
        spline_kernel<<<C, 128, 0, stream>>>(raw, xc,
                                             out_p + (size_t)cs * DIM, lad_p + cs);
    }
}

// Round 4
// 451.579 us; speedup vs baseline: 1.1003x; 1.1003x over previous
//
#include <hip/hip_runtime.h>
#include <hip/hip_bf16.h>

// Problem constants (from reference)
#define BATCH 16384
#define DIM   128
#define HID   1024
#define NK    8
#define OPD   25          // 3*K+1
#define N3    (DIM*OPD)   // 3200

typedef __attribute__((ext_vector_type(8))) short  short8;   // 8 bf16 (4 VGPRs)
typedef __attribute__((ext_vector_type(4))) float  floatx4;  // MFMA C/D frag
typedef unsigned int u32;

// async global->LDS, 16B per lane. HW semantics: dst = wave-uniform base +
// lane*16 (m104/m108) — LDS chunk is dense in lane order; we choose WHICH
// global 16B each lane fetches to implement the XOR bank swizzle.
__device__ __forceinline__ void async_copy16(const unsigned short* g,
                                             unsigned short* l) {
    __builtin_amdgcn_global_load_lds(
        (const __attribute__((address_space(1))) u32*)g,
        (__attribute__((address_space(3))) u32*)l,
        16, 0, 0);
}

// ---------------------------------------------------------------- prep kernels
__global__ void cvt_bf16_kernel(const float* __restrict__ in,
                                __hip_bfloat16* __restrict__ out, int n) {
    int i = blockIdx.x * blockDim.x + threadIdx.x;
    if (i < n) out[i] = __float2bfloat16(in[i]);
}

__global__ void maskmul_bf16_kernel(const float* __restrict__ w,
                                    const float* __restrict__ m,
                                    __hip_bfloat16* __restrict__ out, int n) {
    int i = blockIdx.x * blockDim.x + threadIdx.x;
    if (i < n) out[i] = __float2bfloat16(w[i] * m[i]);
}

// ---------------------------------------------------------------- GEMM
// C[M,N] = A[M,K] * Bw[N,K]^T  (+bias, optional silu->bf16)
// 128x128 tile, BK=64, 256 threads (4 waves, 2x2), each wave 64x64 via 4x4
// mfma_f32_16x16x32_bf16. Staging: global_load_lds width=16 with XOR-swizzled
// LDS chunks (physical chunk = logical ^ (row&7)) -> ds_read_b128 lands
// 2 lanes/bank (free, m136) instead of 16-way conflicts.
// Block-ID swizzle: runs of GY consecutive blocks share one B tile and sweep
// GY A-panels (group working set ~10MB) for L2/L3 temporal locality.
template<int SILU>
__global__ __launch_bounds__(256) void gemm_bt_kernel(
    const unsigned short* __restrict__ A,   // M x K bf16 bits
    const unsigned short* __restrict__ Bw,  // N x K bf16 bits
    const float* __restrict__ bias,         // N
    void* __restrict__ Cout,                // SILU? bf16 : float, M x N
    int M, int N, int Kd)
{
    constexpr int BM = 128, BN = 128, BK = 64;
    __shared__ unsigned short As[BM * BK];   // 16 KB, swizzled row-major
    __shared__ unsigned short Bs[BN * BK];   // 16 KB

    // ---- block swizzle: y fastest within groups of GY rows ----
    const int bid = blockIdx.y * gridDim.x + blockIdx.x;
    const int GY  = (gridDim.y >= 16) ? 16 : gridDim.y;   // gridDim.y is pow2
    const int per_group = gridDim.x * GY;
    const int g  = bid / per_group;
    const int rr = bid % per_group;
    const int bn = (rr / GY) * BN;
    const int bm = (g * GY + (rr % GY)) * BM;

    const int t    = threadIdx.x;
    const int lane = t & 63;
    const int w    = t >> 6;
    const int wr   = (w >> 1) * 64;   // wave m offset in tile
    const int wc   = (w & 1) * 64;    // wave n offset in tile
    const int lr   = lane & 15;
    const int quad = lane >> 4;
    const int lxor = lr & 7;          // row&7 for fragment rows (row = ..16.. + lr)

    floatx4 acc[4][4] = {};

    // staging geometry: 16 segments of 1024B per tile; wave w owns segs
    // w*4..w*4+3. Segment q covers rows q*8..q*8+7. Lane l -> row q*8 + (l>>3),
    // LDS offset l*16B (dense). Global chunk swizzled: c = (l&7) ^ (l>>3).
    const int lrow = lane >> 3;                      // 0..7
    const int lcol = ((lane & 7) ^ lrow) * 8;        // shorts, swizzled chunk

    for (int k0 = 0; k0 < Kd; k0 += BK) {
        __syncthreads();               // previous compute done before overwrite
        #pragma unroll
        for (int p = 0; p < 4; p++) {
            const int q = w * 4 + p;
            const int r = q * 8 + lrow;
            async_copy16(&A[(size_t)(bm + r) * Kd + k0 + lcol],
                         &As[q * 512 + lane * 8]);
            async_copy16(&Bw[(size_t)(bn + r) * Kd + k0 + lcol],
                         &Bs[q * 512 + lane * 8]);
        }
        __syncthreads();               // drains vmcnt -> tiles visible
        #pragma unroll
        for (int ks = 0; ks < BK; ks += 32) {
            const int cbase = (ks >> 3) + quad;      // logical chunk 0..7
            const int coff  = (cbase ^ lxor) * 8;    // physical, shorts
            short8 af[4], bfr[4];
            #pragma unroll
            for (int i = 0; i < 4; i++)
                af[i] = *(const short8*)&As[(wr + i * 16 + lr) * BK + coff];
            #pragma unroll
            for (int j = 0; j < 4; j++)
                bfr[j] = *(const short8*)&Bs[(wc + j * 16 + lr) * BK + coff];
            #pragma unroll
            for (int i = 0; i < 4; i++)
                #pragma unroll
                for (int j = 0; j < 4; j++)
                    acc[i][j] = __builtin_amdgcn_mfma_f32_16x16x32_bf16(
                        af[i], bfr[j], acc[i][j], 0, 0, 0);
        }
    }

    // epilogue
    #pragma unroll
    for (int j = 0; j < 4; j++) {
        const int col = bn + wc + j * 16 + lr;
        const float bv = bias[col];
        #pragma unroll
        for (int i = 0; i < 4; i++) {
            const int rowb = bm + wr + i * 16 + quad * 4;
            #pragma unroll
            for (int r = 0; r < 4; r++) {
                float v = acc[i][j][r] + bv;
                const size_t idx = (size_t)(rowb + r) * N + col;
                if (SILU) {
                    v = v / (1.f + expf(-v));
                    ((__hip_bfloat16*)Cout)[idx] = __float2bfloat16(v);
                } else {
                    ((float*)Cout)[idx] = v;
                }
            }
        }
    }
}

// ---------------------------------------------------------------- spline
// One block per batch row, one thread per dim. Row staged via coalesced
// float4 loads into LDS; per-thread reads at stride 25 dwords (25 coprime 32
// -> 2-way bank aliasing = free). All K=8 arrays fully unrolled.
__global__ __launch_bounds__(128) void spline_kernel(
    const float* __restrict__ raw, const float* __restrict__ x,
    float* __restrict__ out, float* __restrict__ lad)
{
    __shared__ float rowbuf[N3];   // 12.8 KB
    const int b = blockIdx.x;
    const int d = threadIdx.x;

    const float4* src = (const float4*)(raw + (size_t)b * N3);
    for (int i = threadIdx.x; i < N3 / 4; i += 128)
        ((float4*)rowbuf)[i] = src[i];
    __syncthreads();

    const float* r = rowbuf + d * OPD;

    float uw[NK], uh[NK], ud[NK + 1];
    #pragma unroll
    for (int j = 0; j < NK; j++)     uw[j] = r[j];
    #pragma unroll
    for (int j = 0; j < NK; j++)     uh[j] = r[NK + j];
    #pragma unroll
    for (int j = 0; j < NK + 1; j++) ud[j] = r[2 * NK + j];

    float cw[NK + 1], ch[NK + 1], dd[NK + 1];
    // widths: softmax -> affine -> cumsum -> normalize
    {
        float mx = uw[0];
        #pragma unroll
        for (int j = 1; j < NK; j++) mx = fmaxf(mx, uw[j]);
        float e[NK], s = 0.f;
        #pragma unroll
        for (int j = 0; j < NK; j++) { e[j] = expf(uw[j] - mx); s += e[j]; }
        const float inv = 1.f / s;
        cw[0] = 0.f;
        #pragma unroll
        for (int j = 0; j < NK; j++) cw[j + 1] = cw[j] + (0.001f + 0.992f * e[j] * inv);
        const float icn = 1.f / fmaxf(cw[NK], 1e-12f);
        #pragma unroll
        for (int j = 0; j <= NK; j++) cw[j] *= icn;
    }
    // heights: same
    {
        float mx = uh[0];
        #pragma unroll
        for (int j = 1; j < NK; j++) mx = fmaxf(mx, uh[j]);
        float e[NK], s = 0.f;
        #pragma unroll
        for (int j = 0; j < NK; j++) { e[j] = expf(uh[j] - mx); s += e[j]; }
        const float inv = 1.f / s;
        ch[0] = 0.f;
        #pragma unroll
        for (int j = 0; j < NK; j++) ch[j + 1] = ch[j] + (0.001f + 0.992f * e[j] * inv);
        const float icn = 1.f / fmaxf(ch[NK], 1e-12f);
        #pragma unroll
        for (int j = 0; j <= NK; j++) ch[j] *= icn;
    }
    // derivatives: 0.001 + softplus
    #pragma unroll
    for (int j = 0; j <= NK; j++) {
        const float u = ud[j];
        dd[j] = 0.001f + ((u > 20.f) ? u : log1pf(expf(u)));
    }

    const float xv = x[(size_t)b * DIM + d];
    const bool inside = (xv >= -3.f) && (xv <= 3.f);
    float xs = (xv + 3.f) * (1.f / 6.f);
    xs = fminf(fmaxf(xs, 0.f), 1.f);

    int bid = 0;   // cw[0]=0 <= xs always
    #pragma unroll
    for (int j = 1; j <= NK; j++) if (xs >= cw[j]) bid = j;
    if (bid > NK - 1) bid = NK - 1;

    float xk = 0.f, wk = 0.f, yk = 0.f, hk = 0.f, dk = 0.f, dk1 = 0.f;
    #pragma unroll
    for (int j = 0; j < NK; j++) if (bid == j) {
        xk = cw[j]; wk = cw[j + 1] - cw[j];
        yk = ch[j]; hk = ch[j + 1] - ch[j];
        dk = dd[j]; dk1 = dd[j + 1];
    }

    float t = (xs - xk) / (wk + 1e-12f);
    t = fminf(fmaxf(t, 0.f), 1.f);
    const float a   = (hk + 1e-12f) / (wk + 1e-12f);
    const float omt = 1.f - t;
    const float tt1 = t * omt;
    const float num = a * t * t + dk * tt1;
    const float den = a + (dk + dk1 - 2.f * a) * tt1;
    const float s   = num / (den + 1e-12f);
    const float y   = (yk + hk * s) * 6.f - 3.f;
    const float dnum = a * a * (dk1 * t * t + 2.f * a * tt1 + dk * omt * omt);
    const float dydx = dnum / (den * den + 1e-12f);

    out[(size_t)b * DIM + d] = inside ? y : xv;
    float l = inside ? logf(fmaxf(dydx, 1e-12f)) : 0.f;

    // logdet reduction over 128 threads (2 waves)
    #pragma unroll
    for (int off = 32; off > 0; off >>= 1) l += __shfl_down(l, off, 64);
    __shared__ float lsum[2];
    if ((threadIdx.x & 63) == 0) lsum[threadIdx.x >> 6] = l;
    __syncthreads();
    if (threadIdx.x == 0) lad[b] = lsum[0] + lsum[1];
}

// ---------------------------------------------------------------- launch
extern "C" void kernel_launch(void* const* d_in, const int* in_sizes, int n_in,
                              void* d_out, int out_size, void* d_ws, size_t ws_size,
                              hipStream_t stream) {
    const float* x  = (const float*)d_in[0];
    const float* W1 = (const float*)d_in[1];
    const float* b1 = (const float*)d_in[2];
    const float* W2 = (const float*)d_in[3];
    const float* b2 = (const float*)d_in[4];
    const float* W3 = (const float*)d_in[5];
    const float* b3 = (const float*)d_in[6];
    const float* m1 = (const float*)d_in[7];
    const float* m2 = (const float*)d_in[8];
    const float* m3 = (const float*)d_in[9];

    // ---- adaptive batch chunking so the workspace always fits ----
    // static (weights, bf16): w1b 256KB + w2b 2MB + w3b 6.25MB = 8,912,896 B
    // per-chunk C: xb 256C + h1b 2048C + h2b 2048C + raw(fp32) 12800C = 17152C
    constexpr size_t W_BYTES = (size_t)HID * DIM * 2 + (size_t)HID * HID * 2
                             + (size_t)N3 * HID * 2;             // 8,912,896
    int C = BATCH;
    while (C > 512 && W_BYTES + (size_t)17152 * C > ws_size) C >>= 1;
    // C=16384 -> 290MB, 8192 -> 149MB, 4096 -> 79MB, 2048 -> 44MB, 1024 -> 26.5MB

    char* ws = (char*)d_ws;
    const size_t OFF_W1B = 0;
    const size_t OFF_W2B = OFF_W1B + (size_t)HID * DIM * 2;
    const size_t OFF_W3B = OFF_W2B + (size_t)HID * HID * 2;
    const size_t OFF_XB  = OFF_W3B + (size_t)N3 * HID * 2;       // 8,912,896
    const size_t OFF_H1B = OFF_XB  + (size_t)C * DIM * 2;
    const size_t OFF_H2B = OFF_H1B + (size_t)C * HID * 2;
    const size_t OFF_RAW = OFF_H2B + (size_t)C * HID * 2;

    __hip_bfloat16* w1b = (__hip_bfloat16*)(ws + OFF_W1B);
    __hip_bfloat16* w2b = (__hip_bfloat16*)(ws + OFF_W2B);
    __hip_bfloat16* w3b = (__hip_bfloat16*)(ws + OFF_W3B);
    __hip_bfloat16* xb  = (__hip_bfloat16*)(ws + OFF_XB);
    __hip_bfloat16* h1b = (__hip_bfloat16*)(ws + OFF_H1B);
    __hip_bfloat16* h2b = (__hip_bfloat16*)(ws + OFF_H2B);
    float*          raw = (float*)(ws + OFF_RAW);

    // weight prep (once)
    maskmul_bf16_kernel<<<(HID * DIM) / 256, 256, 0, stream>>>(W1, m1, w1b, HID * DIM);
    maskmul_bf16_kernel<<<(HID * HID) / 256, 256, 0, stream>>>(W2, m2, w2b, HID * HID);
    maskmul_bf16_kernel<<<(N3 * HID) / 256, 256, 0, stream>>>(W3, m3, w3b, N3 * HID);

    float* out_p = (float*)d_out;
    float* lad_p = out_p + (size_t)BATCH * DIM;

    for (int cs = 0; cs < BATCH; cs += C) {
        const float* xc = x + (size_t)cs * DIM;
        cvt_bf16_kernel<<<(C * DIM) / 256, 256, 0, stream>>>(xc, xb, C * DIM);
        gemm_bt_kernel<1><<<dim3(HID / 128, C / 128), 256, 0, stream>>>(
            (const unsigned short*)xb, (const unsigned short*)w1b, b1, h1b,
            C, HID, DIM);
        gemm_bt_kernel<1><<<dim3(HID / 128, C / 128), 256, 0, stream>>>(
            (const unsigned short*)h1b, (const unsigned short*)w2b, b2, h2b,
            C, HID, HID);
        gemm_bt_kernel<0><<<dim3(N3 / 128, C / 128), 256, 0, stream>>>(
            (const unsigned short*)h2b, (const unsigned short*)w3b, b3, raw,
            C, N3, HID);
        spline_kernel<<<C, 128, 0, stream>>>(raw, xc,
                                             out_p + (size_t)cs * DIM, lad_p + cs);
    }
}

// Round 5
// 431.649 us; speedup vs baseline: 1.1511x; 1.0462x over previous
//
#include <hip/hip_runtime.h>
#include <hip/hip_bf16.h>

// Problem constants (from reference)
#define BATCH 16384
#define DIM   128
#define HID   1024
#define NK    8
#define OPD   25          // 3*K+1
#define N3    (DIM*OPD)   // 3200
#define NP    3328        // 26 tiles x 128 cols; tile = 5 dims x 25 params + 3 pad

typedef __attribute__((ext_vector_type(8))) short  short8;   // 8 bf16 (4 VGPRs)
typedef __attribute__((ext_vector_type(4))) float  floatx4;  // MFMA C/D frag
typedef unsigned int u32;

// async global->LDS, 16B per lane. dst = wave-uniform base + lane*16.
__device__ __forceinline__ void async_copy16(const unsigned short* g,
                                             unsigned short* l) {
    __builtin_amdgcn_global_load_lds(
        (const __attribute__((address_space(1))) u32*)g,
        (__attribute__((address_space(3))) u32*)l,
        16, 0, 0);
}

// ---------------------------------------------------------------- prep kernels
__global__ void cvt_bf16_kernel(const float* __restrict__ in,
                                __hip_bfloat16* __restrict__ out, int n) {
    int i = blockIdx.x * blockDim.x + threadIdx.x;
    if (i < n) out[i] = __float2bfloat16(in[i]);
}

__global__ void maskmul_bf16_kernel(const float* __restrict__ w,
                                    const float* __restrict__ m,
                                    __hip_bfloat16* __restrict__ out, int n) {
    int i = blockIdx.x * blockDim.x + threadIdx.x;
    if (i < n) out[i] = __float2bfloat16(w[i] * m[i]);
}

// W3 permuted+padded: padded col c = t*128+s <-> source col t*125+s (s<125).
__global__ void maskmul_w3p_kernel(const float* __restrict__ w,
                                   const float* __restrict__ m,
                                   __hip_bfloat16* __restrict__ out) {
    int i = blockIdx.x * blockDim.x + threadIdx.x;   // over NP*HID
    int c = i >> 10, k = i & 1023;
    int s = c & 127, t = c >> 7;
    float v = 0.f;
    if (s < 125) { int src = (t * 125 + s) * HID + k; v = w[src] * m[src]; }
    out[i] = __float2bfloat16(v);
}

__global__ void lad_init_kernel(float* __restrict__ lad) {
    lad[blockIdx.x * 256 + threadIdx.x] = 0.f;
}

// ---------------------------------------------------------------- spline eval
// p[0..7]=uw, p[8..15]=uh, p[16..24]=ud. Verified math (rounds 2-4).
__device__ __forceinline__ void spline_eval(const float* __restrict__ p,
                                            float xv, float& yout, float& lout) {
    float cw[NK + 1], ch[NK + 1], dd[NK + 1];
    {
        float mx = p[0];
        #pragma unroll
        for (int j = 1; j < NK; j++) mx = fmaxf(mx, p[j]);
        float e[NK], s = 0.f;
        #pragma unroll
        for (int j = 0; j < NK; j++) { e[j] = expf(p[j] - mx); s += e[j]; }
        const float inv = 1.f / s;
        cw[0] = 0.f;
        #pragma unroll
        for (int j = 0; j < NK; j++) cw[j + 1] = cw[j] + (0.001f + 0.992f * e[j] * inv);
        const float icn = 1.f / fmaxf(cw[NK], 1e-12f);
        #pragma unroll
        for (int j = 0; j <= NK; j++) cw[j] *= icn;
    }
    {
        float mx = p[8];
        #pragma unroll
        for (int j = 1; j < NK; j++) mx = fmaxf(mx, p[8 + j]);
        float e[NK], s = 0.f;
        #pragma unroll
        for (int j = 0; j < NK; j++) { e[j] = expf(p[8 + j] - mx); s += e[j]; }
        const float inv = 1.f / s;
        ch[0] = 0.f;
        #pragma unroll
        for (int j = 0; j < NK; j++) ch[j + 1] = ch[j] + (0.001f + 0.992f * e[j] * inv);
        const float icn = 1.f / fmaxf(ch[NK], 1e-12f);
        #pragma unroll
        for (int j = 0; j <= NK; j++) ch[j] *= icn;
    }
    #pragma unroll
    for (int j = 0; j <= NK; j++) {
        const float u = p[16 + j];
        dd[j] = 0.001f + ((u > 20.f) ? u : log1pf(expf(u)));
    }

    const bool inside = (xv >= -3.f) && (xv <= 3.f);
    float xs = (xv + 3.f) * (1.f / 6.f);
    xs = fminf(fmaxf(xs, 0.f), 1.f);

    int bid = 0;
    #pragma unroll
    for (int j = 1; j <= NK; j++) if (xs >= cw[j]) bid = j;
    if (bid > NK - 1) bid = NK - 1;

    float xk = 0.f, wk = 0.f, yk = 0.f, hk = 0.f, dk = 0.f, dk1 = 0.f;
    #pragma unroll
    for (int j = 0; j < NK; j++) if (bid == j) {
        xk = cw[j]; wk = cw[j + 1] - cw[j];
        yk = ch[j]; hk = ch[j + 1] - ch[j];
        dk = dd[j]; dk1 = dd[j + 1];
    }

    float t = (xs - xk) / (wk + 1e-12f);
    t = fminf(fmaxf(t, 0.f), 1.f);
    const float a   = (hk + 1e-12f) / (wk + 1e-12f);
    const float omt = 1.f - t;
    const float tt1 = t * omt;
    const float num = a * t * t + dk * tt1;
    const float den = a + (dk + dk1 - 2.f * a) * tt1;
    const float s   = num / (den + 1e-12f);
    const float y   = (yk + hk * s) * 6.f - 3.f;
    const float dnum = a * a * (dk1 * t * t + 2.f * a * tt1 + dk * omt * omt);
    const float dydx = dnum / (den * den + 1e-12f);

    yout = inside ? y : xv;
    lout = inside ? logf(fmaxf(dydx, 1e-12f)) : 0.f;
}

// ---------------------------------------------------------------- GEMM (1,2)
// C[M,N] = A[M,K] * Bw[N,K]^T + bias, silu -> bf16. Same proven structure.
__global__ __launch_bounds__(256) void gemm_bt_kernel(
    const unsigned short* __restrict__ A,
    const unsigned short* __restrict__ Bw,
    const float* __restrict__ bias,
    __hip_bfloat16* __restrict__ Cout,
    int M, int N, int Kd)
{
    constexpr int BM = 128, BN = 128, BK = 64;
    __shared__ unsigned short As[BM * BK];
    __shared__ unsigned short Bs[BN * BK];

    const int bid = blockIdx.y * gridDim.x + blockIdx.x;
    const int GY  = (gridDim.y >= 16) ? 16 : gridDim.y;
    const int per_group = gridDim.x * GY;
    const int g  = bid / per_group;
    const int rr = bid % per_group;
    const int bn = (rr / GY) * BN;
    const int bm = (g * GY + (rr % GY)) * BM;

    const int t    = threadIdx.x;
    const int lane = t & 63;
    const int w    = t >> 6;
    const int wr   = (w >> 1) * 64;
    const int wc   = (w & 1) * 64;
    const int lr   = lane & 15;
    const int quad = lane >> 4;
    const int lxor = lr & 7;

    floatx4 acc[4][4] = {};

    const int lrow = lane >> 3;
    const int lcol = ((lane & 7) ^ lrow) * 8;

    for (int k0 = 0; k0 < Kd; k0 += BK) {
        __syncthreads();
        #pragma unroll
        for (int p = 0; p < 4; p++) {
            const int q = w * 4 + p;
            const int r = q * 8 + lrow;
            async_copy16(&A[(size_t)(bm + r) * Kd + k0 + lcol],
                         &As[q * 512 + lane * 8]);
            async_copy16(&Bw[(size_t)(bn + r) * Kd + k0 + lcol],
                         &Bs[q * 512 + lane * 8]);
        }
        __syncthreads();
        #pragma unroll
        for (int ks = 0; ks < BK; ks += 32) {
            const int cbase = (ks >> 3) + quad;
            const int coff  = (cbase ^ lxor) * 8;
            short8 af[4], bfr[4];
            #pragma unroll
            for (int i = 0; i < 4; i++)
                af[i] = *(const short8*)&As[(wr + i * 16 + lr) * BK + coff];
            #pragma unroll
            for (int j = 0; j < 4; j++)
                bfr[j] = *(const short8*)&Bs[(wc + j * 16 + lr) * BK + coff];
            #pragma unroll
            for (int i = 0; i < 4; i++)
                #pragma unroll
                for (int j = 0; j < 4; j++)
                    acc[i][j] = __builtin_amdgcn_mfma_f32_16x16x32_bf16(
                        af[i], bfr[j], acc[i][j], 0, 0, 0);
        }
    }

    #pragma unroll
    for (int j = 0; j < 4; j++) {
        const int col = bn + wc + j * 16 + lr;
        const float bv = bias[col];
        #pragma unroll
        for (int i = 0; i < 4; i++) {
            const int rowb = bm + wr + i * 16 + quad * 4;
            #pragma unroll
            for (int r = 0; r < 4; r++) {
                float v = acc[i][j][r] + bv;
                v = v / (1.f + expf(-v));
                Cout[(size_t)(rowb + r) * N + col] = __float2bfloat16(v);
            }
        }
    }
}

// ---------------------------------------------------------------- GEMM3+spline
// C = h2 * w3p^T (N=NP, tile t holds dims t*5..t*5+4 at cols s=ds*25+o).
// Epilogue: per 64-row half, owning waves dump bias-added acc to LDS
// (64 x 133 fp32), then all threads run spline tasks (64 rows x 5 dims),
// write out directly and atomicAdd logdet per row.
__global__ __launch_bounds__(256) void gemm3_spline_kernel(
    const unsigned short* __restrict__ A,    // h2b M x HID
    const unsigned short* __restrict__ Bw,   // w3p NP x HID
    const float* __restrict__ b3,            // N3 (original layout)
    const float* __restrict__ x,             // M x DIM fp32
    float* __restrict__ out,                 // M x DIM
    float* __restrict__ lad,                 // M, pre-zeroed
    int M)
{
    constexpr int BM = 128, BN = 128, BK = 64, Kd = HID;
    constexpr int LSE = 133;                         // epilogue stride (gcd(133,32)=1)
    __shared__ __align__(16) char smem[64 * LSE * 4]; // 34,048 B
    unsigned short* As = (unsigned short*)smem;       // 16 KB
    unsigned short* Bs = (unsigned short*)(smem + BM * BK * 2);
    float* eb = (float*)smem;

    const int bid = blockIdx.y * gridDim.x + blockIdx.x;
    const int GY  = 16;                               // gridDim.y = 128
    const int per_group = gridDim.x * GY;
    const int g  = bid / per_group;
    const int rr = bid % per_group;
    const int tile = rr / GY;                         // 0..25
    const int bn = tile * BN;
    const int bm = (g * GY + (rr % GY)) * BM;

    const int t    = threadIdx.x;
    const int lane = t & 63;
    const int w    = t >> 6;
    const int wr   = (w >> 1) * 64;
    const int wc   = (w & 1) * 64;
    const int lr   = lane & 15;
    const int quad = lane >> 4;
    const int lxor = lr & 7;

    floatx4 acc[4][4] = {};

    const int lrow = lane >> 3;
    const int lcol = ((lane & 7) ^ lrow) * 8;

    for (int k0 = 0; k0 < Kd; k0 += BK) {
        __syncthreads();
        #pragma unroll
        for (int p = 0; p < 4; p++) {
            const int q = w * 4 + p;
            const int r = q * 8 + lrow;
            async_copy16(&A[(size_t)(bm + r) * Kd + k0 + lcol],
                         &As[q * 512 + lane * 8]);
            async_copy16(&Bw[(size_t)(bn + r) * Kd + k0 + lcol],
                         &Bs[q * 512 + lane * 8]);
        }
        __syncthreads();
        #pragma unroll
        for (int ks = 0; ks < BK; ks += 32) {
            const int cbase = (ks >> 3) + quad;
            const int coff  = (cbase ^ lxor) * 8;
            short8 af[4], bfr[4];
            #pragma unroll
            for (int i = 0; i < 4; i++)
                af[i] = *(const short8*)&As[(wr + i * 16 + lr) * BK + coff];
            #pragma unroll
            for (int j = 0; j < 4; j++)
                bfr[j] = *(const short8*)&Bs[(wc + j * 16 + lr) * BK + coff];
            #pragma unroll
            for (int i = 0; i < 4; i++)
                #pragma unroll
                for (int j = 0; j < 4; j++)
                    acc[i][j] = __builtin_amdgcn_mfma_f32_16x16x32_bf16(
                        af[i], bfr[j], acc[i][j], 0, 0, 0);
        }
    }

    // ---- fused epilogue: two 64-row halves ----
    #pragma unroll 1
    for (int h = 0; h < 2; h++) {
        __syncthreads();                 // LDS free for reuse
        if ((w >> 1) == h) {
            #pragma unroll
            for (int j = 0; j < 4; j++) {
                const int s = wc + j * 16 + lr;
                const float bv = (s < 125) ? b3[tile * 125 + s] : 0.f;
                #pragma unroll
                for (int i = 0; i < 4; i++) {
                    const int lrw = i * 16 + quad * 4;   // 0..63 within half
                    #pragma unroll
                    for (int r2 = 0; r2 < 4; r2++)
                        eb[(lrw + r2) * LSE + s] = acc[i][j][r2] + bv;
                }
            }
        }
        __syncthreads();
        // 320 tasks = 64 rows x 5 dims
        #pragma unroll 1
        for (int q = t; q < 320; q += 256) {
            const int r  = q & 63;
            const int ds = q >> 6;
            const int dim = tile * 5 + ds;
            if (dim < DIM) {
                const float* p = eb + r * LSE + ds * 25;
                const int grow = bm + h * 64 + r;
                const float xv = x[(size_t)grow * DIM + dim];
                float y, l;
                spline_eval(p, xv, y, l);
                out[(size_t)grow * DIM + dim] = y;
                atomicAdd(&lad[grow], l);
            }
        }
    }
}

// ---------------------------------------------------------------- launch
extern "C" void kernel_launch(void* const* d_in, const int* in_sizes, int n_in,
                              void* d_out, int out_size, void* d_ws, size_t ws_size,
                              hipStream_t stream) {
    const float* x  = (const float*)d_in[0];
    const float* W1 = (const float*)d_in[1];
    const float* b1 = (const float*)d_in[2];
    const float* W2 = (const float*)d_in[3];
    const float* b2 = (const float*)d_in[4];
    const float* W3 = (const float*)d_in[5];
    const float* b3 = (const float*)d_in[6];
    const float* m1 = (const float*)d_in[7];
    const float* m2 = (const float*)d_in[8];
    const float* m3 = (const float*)d_in[9];

    // workspace (raw eliminated): total ~81 MB (fits: ws >= 149 MB per round 2)
    char* ws = (char*)d_ws;
    const size_t OFF_W1B = 0;
    const size_t OFF_W2B = OFF_W1B + (size_t)HID * DIM * 2;      //   256 KB
    const size_t OFF_W3P = OFF_W2B + (size_t)HID * HID * 2;      //  +2 MB
    const size_t OFF_XB  = OFF_W3P + (size_t)NP * HID * 2;       //  +6.8 MB
    const size_t OFF_H1B = OFF_XB  + (size_t)BATCH * DIM * 2;    //  +4.2 MB
    const size_t OFF_H2B = OFF_H1B + (size_t)BATCH * HID * 2;    // +33.6 MB
    // end: OFF_H2B + 33.6 MB ~= 80.4 MB

    __hip_bfloat16* w1b = (__hip_bfloat16*)(ws + OFF_W1B);
    __hip_bfloat16* w2b = (__hip_bfloat16*)(ws + OFF_W2B);
    __hip_bfloat16* w3p = (__hip_bfloat16*)(ws + OFF_W3P);
    __hip_bfloat16* xb  = (__hip_bfloat16*)(ws + OFF_XB);
    __hip_bfloat16* h1b = (__hip_bfloat16*)(ws + OFF_H1B);
    __hip_bfloat16* h2b = (__hip_bfloat16*)(ws + OFF_H2B);

    float* out_p = (float*)d_out;
    float* lad_p = out_p + (size_t)BATCH * DIM;

    // prep
    maskmul_bf16_kernel<<<(HID * DIM) / 256, 256, 0, stream>>>(W1, m1, w1b, HID * DIM);
    maskmul_bf16_kernel<<<(HID * HID) / 256, 256, 0, stream>>>(W2, m2, w2b, HID * HID);
    maskmul_w3p_kernel<<<((size_t)NP * HID) / 256, 256, 0, stream>>>(W3, m3, w3p);
    cvt_bf16_kernel<<<(BATCH * DIM) / 256, 256, 0, stream>>>(x, xb, BATCH * DIM);
    lad_init_kernel<<<BATCH / 256, 256, 0, stream>>>(lad_p);

    // GEMMs
    gemm_bt_kernel<<<dim3(HID / 128, BATCH / 128), 256, 0, stream>>>(
        (const unsigned short*)xb, (const unsigned short*)w1b, b1, h1b,
        BATCH, HID, DIM);
    gemm_bt_kernel<<<dim3(HID / 128, BATCH / 128), 256, 0, stream>>>(
        (const unsigned short*)h1b, (const unsigned short*)w2b, b2, h2b,
        BATCH, HID, HID);
    gemm3_spline_kernel<<<dim3(NP / 128, BATCH / 128), 256, 0, stream>>>(
        (const unsigned short*)h2b, (const unsigned short*)w3p, b3, x,
        out_p, lad_p, BATCH);
}

// Round 6
// 383.329 us; speedup vs baseline: 1.2962x; 1.1261x over previous
//
#include <hip/hip_runtime.h>
#include <hip/hip_bf16.h>

// Problem constants (from reference)
#define BATCH 16384
#define DIM   128
#define HID   1024
#define NK    8
#define OPD   25          // 3*K+1
#define N3    (DIM*OPD)   // 3200
#define NP    3328        // 26 tiles x 128 cols; tile = 5 dims x 25 params + 3 pad

typedef __attribute__((ext_vector_type(8))) short  short8;   // 8 bf16 (4 VGPRs)
typedef __attribute__((ext_vector_type(4))) float  floatx4;  // MFMA C/D frag
typedef unsigned int u32;

// async global->LDS, 16B per lane. dst = wave-uniform base + lane*16.
__device__ __forceinline__ void async_copy16(const unsigned short* g,
                                             unsigned short* l) {
    __builtin_amdgcn_global_load_lds(
        (const __attribute__((address_space(1))) u32*)g,
        (__attribute__((address_space(3))) u32*)l,
        16, 0, 0);
}

// ---------------------------------------------------------------- prep kernels
__global__ void cvt_bf16_kernel(const float* __restrict__ in,
                                __hip_bfloat16* __restrict__ out, int n) {
    int i = blockIdx.x * blockDim.x + threadIdx.x;
    if (i < n) out[i] = __float2bfloat16(in[i]);
}

__global__ void maskmul_bf16_kernel(const float* __restrict__ w,
                                    const float* __restrict__ m,
                                    __hip_bfloat16* __restrict__ out, int n) {
    int i = blockIdx.x * blockDim.x + threadIdx.x;
    if (i < n) out[i] = __float2bfloat16(w[i] * m[i]);
}

// W3 permuted+padded: padded col c = t*128+s <-> source col t*125+s (s<125).
__global__ void maskmul_w3p_kernel(const float* __restrict__ w,
                                   const float* __restrict__ m,
                                   __hip_bfloat16* __restrict__ out) {
    int i = blockIdx.x * blockDim.x + threadIdx.x;   // over NP*HID
    int c = i >> 10, k = i & 1023;
    int s = c & 127, t = c >> 7;
    float v = 0.f;
    if (s < 125) { int src = (t * 125 + s) * HID + k; v = w[src] * m[src]; }
    out[i] = __float2bfloat16(v);
}

__global__ void lad_init_kernel(float* __restrict__ lad) {
    lad[blockIdx.x * 256 + threadIdx.x] = 0.f;
}

// ---------------------------------------------------------------- spline eval
// p[0..7]=uw, p[8..15]=uh, p[16..24]=ud. Optimized: softplus only on the 2
// selected derivative params; selection on unnormalized cumsums; normalize
// only selected values. Math identical to verified rounds 2-5 version.
__device__ __forceinline__ void spline_eval(const float* __restrict__ p,
                                            float xv, float& yout, float& lout) {
    float cw[NK + 1], ch[NK + 1];
    {
        float mx = p[0];
        #pragma unroll
        for (int j = 1; j < NK; j++) mx = fmaxf(mx, p[j]);
        float e[NK], s = 0.f;
        #pragma unroll
        for (int j = 0; j < NK; j++) { e[j] = expf(p[j] - mx); s += e[j]; }
        const float inv = 1.f / s;
        cw[0] = 0.f;
        #pragma unroll
        for (int j = 0; j < NK; j++) cw[j + 1] = cw[j] + (0.001f + 0.992f * e[j] * inv);
    }
    {
        float mx = p[8];
        #pragma unroll
        for (int j = 1; j < NK; j++) mx = fmaxf(mx, p[8 + j]);
        float e[NK], s = 0.f;
        #pragma unroll
        for (int j = 0; j < NK; j++) { e[j] = expf(p[8 + j] - mx); s += e[j]; }
        const float inv = 1.f / s;
        ch[0] = 0.f;
        #pragma unroll
        for (int j = 0; j < NK; j++) ch[j + 1] = ch[j] + (0.001f + 0.992f * e[j] * inv);
    }
    const float icw = 1.f / fmaxf(cw[NK], 1e-12f);
    const float ich = 1.f / fmaxf(ch[NK], 1e-12f);

    const bool inside = (xv >= -3.f) && (xv <= 3.f);
    float xs = (xv + 3.f) * (1.f / 6.f);
    xs = fminf(fmaxf(xs, 0.f), 1.f);
    const float xsc = xs * cw[NK];          // compare in unnormalized domain

    // merged predicated selection (bid implicitly clamped to NK-1)
    float xk = 0.f, wk = cw[1], yk = 0.f, hk = ch[1];
    float uda = p[16], udb = p[17];
    #pragma unroll
    for (int j = 1; j < NK; j++) {
        const bool c = (xsc >= cw[j]);
        xk  = c ? cw[j] : xk;
        wk  = c ? (cw[j + 1] - cw[j]) : wk;
        yk  = c ? ch[j] : yk;
        hk  = c ? (ch[j + 1] - ch[j]) : hk;
        uda = c ? p[16 + j] : uda;
        udb = c ? p[17 + j] : udb;
    }
    xk *= icw; wk *= icw;
    yk *= ich; hk *= ich;

    const float dk  = 0.001f + ((uda > 20.f) ? uda : log1pf(expf(uda)));
    const float dk1 = 0.001f + ((udb > 20.f) ? udb : log1pf(expf(udb)));

    float t = (xs - xk) / (wk + 1e-12f);
    t = fminf(fmaxf(t, 0.f), 1.f);
    const float a   = (hk + 1e-12f) / (wk + 1e-12f);
    const float omt = 1.f - t;
    const float tt1 = t * omt;
    const float num = a * t * t + dk * tt1;
    const float den = a + (dk + dk1 - 2.f * a) * tt1;
    const float s   = num / (den + 1e-12f);
    const float y   = (yk + hk * s) * 6.f - 3.f;
    const float dnum = a * a * (dk1 * t * t + 2.f * a * tt1 + dk * omt * omt);
    const float dydx = dnum / (den * den + 1e-12f);

    yout = inside ? y : xv;
    lout = inside ? logf(fmaxf(dydx, 1e-12f)) : 0.f;
}

// ---------------------------------------------------------------- GEMM (1,2)
// C[M,N] = A[M,K] * Bw[N,K]^T + bias, silu -> bf16. Proven structure:
// global_load_lds w=16, XOR bank swizzle (0 conflicts), block swizzle GY=16.
__global__ __launch_bounds__(256) void gemm_bt_kernel(
    const unsigned short* __restrict__ A,
    const unsigned short* __restrict__ Bw,
    const float* __restrict__ bias,
    __hip_bfloat16* __restrict__ Cout,
    int M, int N, int Kd)
{
    constexpr int BM = 128, BN = 128, BK = 64;
    __shared__ unsigned short As[BM * BK];
    __shared__ unsigned short Bs[BN * BK];

    const int bid = blockIdx.y * gridDim.x + blockIdx.x;
    const int GY  = (gridDim.y >= 16) ? 16 : gridDim.y;
    const int per_group = gridDim.x * GY;
    const int g  = bid / per_group;
    const int rr = bid % per_group;
    const int bn = (rr / GY) * BN;
    const int bm = (g * GY + (rr % GY)) * BM;

    const int t    = threadIdx.x;
    const int lane = t & 63;
    const int w    = t >> 6;
    const int wr   = (w >> 1) * 64;
    const int wc   = (w & 1) * 64;
    const int lr   = lane & 15;
    const int quad = lane >> 4;
    const int lxor = lr & 7;

    floatx4 acc[4][4] = {};

    const int lrow = lane >> 3;
    const int lcol = ((lane & 7) ^ lrow) * 8;

    for (int k0 = 0; k0 < Kd; k0 += BK) {
        __syncthreads();
        #pragma unroll
        for (int p = 0; p < 4; p++) {
            const int q = w * 4 + p;
            const int r = q * 8 + lrow;
            async_copy16(&A[(size_t)(bm + r) * Kd + k0 + lcol],
                         &As[q * 512 + lane * 8]);
            async_copy16(&Bw[(size_t)(bn + r) * Kd + k0 + lcol],
                         &Bs[q * 512 + lane * 8]);
        }
        __syncthreads();
        #pragma unroll
        for (int ks = 0; ks < BK; ks += 32) {
            const int cbase = (ks >> 3) + quad;
            const int coff  = (cbase ^ lxor) * 8;
            short8 af[4], bfr[4];
            #pragma unroll
            for (int i = 0; i < 4; i++)
                af[i] = *(const short8*)&As[(wr + i * 16 + lr) * BK + coff];
            #pragma unroll
            for (int j = 0; j < 4; j++)
                bfr[j] = *(const short8*)&Bs[(wc + j * 16 + lr) * BK + coff];
            #pragma unroll
            for (int i = 0; i < 4; i++)
                #pragma unroll
                for (int j = 0; j < 4; j++)
                    acc[i][j] = __builtin_amdgcn_mfma_f32_16x16x32_bf16(
                        af[i], bfr[j], acc[i][j], 0, 0, 0);
        }
    }

    #pragma unroll
    for (int j = 0; j < 4; j++) {
        const int col = bn + wc + j * 16 + lr;
        const float bv = bias[col];
        #pragma unroll
        for (int i = 0; i < 4; i++) {
            const int rowb = bm + wr + i * 16 + quad * 4;
            #pragma unroll
            for (int r = 0; r < 4; r++) {
                float v = acc[i][j][r] + bv;
                v = v / (1.f + expf(-v));
                Cout[(size_t)(rowb + r) * N + col] = __float2bfloat16(v);
            }
        }
    }
}

// ---------------------------------------------------------------- GEMM3+spline
// C = h2 * w3p^T (N=NP, tile t holds dims t*5..t*5+4 at cols s=ds*25+o).
// Epilogue: per 64-row half, owning waves dump bias-added acc to LDS
// (64 x 133 fp32), then all threads run spline tasks (ds-minor order for
// coalesced x reads), accumulate logdet in LDS, one global atomic per row.
__global__ __launch_bounds__(256) void gemm3_spline_kernel(
    const unsigned short* __restrict__ A,    // h2b M x HID
    const unsigned short* __restrict__ Bw,   // w3p NP x HID
    const float* __restrict__ b3,            // N3 (original layout)
    const float* __restrict__ x,             // M x DIM fp32
    float* __restrict__ out,                 // M x DIM
    float* __restrict__ lad,                 // M, pre-zeroed
    int M)
{
    constexpr int BM = 128, BN = 128, BK = 64, Kd = HID;
    constexpr int LSE = 133;                          // epilogue stride
    __shared__ __align__(16) char smem[64 * LSE * 4 + 128 * 4]; // 34,560 B
    unsigned short* As = (unsigned short*)smem;       // 16 KB
    unsigned short* Bs = (unsigned short*)(smem + BM * BK * 2);
    float* eb     = (float*)smem;
    float* ladacc = (float*)(smem + 64 * LSE * 4);    // [128], outside As/Bs/eb

    const int bid = blockIdx.y * gridDim.x + blockIdx.x;
    const int GY  = 16;                               // gridDim.y = 128
    const int per_group = gridDim.x * GY;
    const int g  = bid / per_group;
    const int rr = bid % per_group;
    const int tile = rr / GY;                         // 0..25
    const int bn = tile * BN;
    const int bm = (g * GY + (rr % GY)) * BM;

    const int t    = threadIdx.x;
    const int lane = t & 63;
    const int w    = t >> 6;
    const int wr   = (w >> 1) * 64;
    const int wc   = (w & 1) * 64;
    const int lr   = lane & 15;
    const int quad = lane >> 4;
    const int lxor = lr & 7;

    if (t < 128) ladacc[t] = 0.f;      // visible after first __syncthreads

    floatx4 acc[4][4] = {};

    const int lrow = lane >> 3;
    const int lcol = ((lane & 7) ^ lrow) * 8;

    for (int k0 = 0; k0 < Kd; k0 += BK) {
        __syncthreads();
        #pragma unroll
        for (int p = 0; p < 4; p++) {
            const int q = w * 4 + p;
            const int r = q * 8 + lrow;
            async_copy16(&A[(size_t)(bm + r) * Kd + k0 + lcol],
                         &As[q * 512 + lane * 8]);
            async_copy16(&Bw[(size_t)(bn + r) * Kd + k0 + lcol],
                         &Bs[q * 512 + lane * 8]);
        }
        __syncthreads();
        #pragma unroll
        for (int ks = 0; ks < BK; ks += 32) {
            const int cbase = (ks >> 3) + quad;
            const int coff  = (cbase ^ lxor) * 8;
            short8 af[4], bfr[4];
            #pragma unroll
            for (int i = 0; i < 4; i++)
                af[i] = *(const short8*)&As[(wr + i * 16 + lr) * BK + coff];
            #pragma unroll
            for (int j = 0; j < 4; j++)
                bfr[j] = *(const short8*)&Bs[(wc + j * 16 + lr) * BK + coff];
            #pragma unroll
            for (int i = 0; i < 4; i++)
                #pragma unroll
                for (int j = 0; j < 4; j++)
                    acc[i][j] = __builtin_amdgcn_mfma_f32_16x16x32_bf16(
                        af[i], bfr[j], acc[i][j], 0, 0, 0);
        }
    }

    // ---- fused epilogue: two 64-row halves ----
    #pragma unroll 1
    for (int h = 0; h < 2; h++) {
        __syncthreads();                 // LDS free for reuse
        if ((w >> 1) == h) {
            #pragma unroll
            for (int j = 0; j < 4; j++) {
                const int s = wc + j * 16 + lr;
                const float bv = (s < 125) ? b3[tile * 125 + s] : 0.f;
                #pragma unroll
                for (int i = 0; i < 4; i++) {
                    const int lrw = i * 16 + quad * 4;   // 0..63 within half
                    #pragma unroll
                    for (int r2 = 0; r2 < 4; r2++)
                        eb[(lrw + r2) * LSE + s] = acc[i][j][r2] + bv;
                }
            }
        }
        __syncthreads();
        // 320 tasks = 64 rows x 5 dims, ds-minor => coalesced x reads
        #pragma unroll 1
        for (int q = t; q < 320; q += 256) {
            const int r  = q / 5;
            const int ds = q % 5;
            const int dim = tile * 5 + ds;
            if (dim < DIM) {
                const float* p = eb + r * LSE + ds * 25;
                const int grow = bm + h * 64 + r;
                const float xv = x[(size_t)grow * DIM + dim];
                float y, l;
                spline_eval(p, xv, y, l);
                out[(size_t)grow * DIM + dim] = y;
                atomicAdd(&ladacc[h * 64 + r], l);
            }
        }
    }
    __syncthreads();
    if (t < 128) atomicAdd(&lad[bm + t], ladacc[t]);
}

// ---------------------------------------------------------------- launch
extern "C" void kernel_launch(void* const* d_in, const int* in_sizes, int n_in,
                              void* d_out, int out_size, void* d_ws, size_t ws_size,
                              hipStream_t stream) {
    const float* x  = (const float*)d_in[0];
    const float* W1 = (const float*)d_in[1];
    const float* b1 = (const float*)d_in[2];
    const float* W2 = (const float*)d_in[3];
    const float* b2 = (const float*)d_in[4];
    const float* W3 = (const float*)d_in[5];
    const float* b3 = (const float*)d_in[6];
    const float* m1 = (const float*)d_in[7];
    const float* m2 = (const float*)d_in[8];
    const float* m3 = (const float*)d_in[9];

    // workspace: total ~81 MB
    char* ws = (char*)d_ws;
    const size_t OFF_W1B = 0;
    const size_t OFF_W2B = OFF_W1B + (size_t)HID * DIM * 2;      //   256 KB
    const size_t OFF_W3P = OFF_W2B + (size_t)HID * HID * 2;      //  +2 MB
    const size_t OFF_XB  = OFF_W3P + (size_t)NP * HID * 2;       //  +6.8 MB
    const size_t OFF_H1B = OFF_XB  + (size_t)BATCH * DIM * 2;    //  +4.2 MB
    const size_t OFF_H2B = OFF_H1B + (size_t)BATCH * HID * 2;    // +33.6 MB

    __hip_bfloat16* w1b = (__hip_bfloat16*)(ws + OFF_W1B);
    __hip_bfloat16* w2b = (__hip_bfloat16*)(ws + OFF_W2B);
    __hip_bfloat16* w3p = (__hip_bfloat16*)(ws + OFF_W3P);
    __hip_bfloat16* xb  = (__hip_bfloat16*)(ws + OFF_XB);
    __hip_bfloat16* h1b = (__hip_bfloat16*)(ws + OFF_H1B);
    __hip_bfloat16* h2b = (__hip_bfloat16*)(ws + OFF_H2B);

    float* out_p = (float*)d_out;
    float* lad_p = out_p + (size_t)BATCH * DIM;

    // prep
    maskmul_bf16_kernel<<<(HID * DIM) / 256, 256, 0, stream>>>(W1, m1, w1b, HID * DIM);
    maskmul_bf16_kernel<<<(HID * HID) / 256, 256, 0, stream>>>(W2, m2, w2b, HID * HID);
    maskmul_w3p_kernel<<<((size_t)NP * HID) / 256, 256, 0, stream>>>(W3, m3, w3p);
    cvt_bf16_kernel<<<(BATCH * DIM) / 256, 256, 0, stream>>>(x, xb, BATCH * DIM);
    lad_init_kernel<<<BATCH / 256, 256, 0, stream>>>(lad_p);

    // GEMMs
    gemm_bt_kernel<<<dim3(HID / 128, BATCH / 128), 256, 0, stream>>>(
        (const unsigned short*)xb, (const unsigned short*)w1b, b1, h1b,
        BATCH, HID, DIM);
    gemm_bt_kernel<<<dim3(HID / 128, BATCH / 128), 256, 0, stream>>>(
        (const unsigned short*)h1b, (const unsigned short*)w2b, b2, h2b,
        BATCH, HID, HID);
    gemm3_spline_kernel<<<dim3(NP / 128, BATCH / 128), 256, 0, stream>>>(
        (const unsigned short*)h2b, (const unsigned short*)w3p, b3, x,
        out_p, lad_p, BATCH);
}